// Round 2
// baseline (212.792 us; speedup 1.0000x reference)
//
#include <hip/hip_runtime.h>
#include <hip/hip_fp16.h>

#define D_ 160
#define H_ 192
#define W_ 160
constexpr int NV = D_ * H_ * W_;   // 4,915,200 (even)

typedef float        f32x4 __attribute__((ext_vector_type(4)));
typedef unsigned int u32x4 __attribute__((ext_vector_type(4)));

// ---------------------------------------------------------------------------
// Pass 1: convert vol f32[NV][4] -> packed half4 (uint2) in d_ws.
// 2 voxels/thread: 32 B read (non-temporal; read-once), 16 B write, coalesced.
// XCD-swizzled so each XCD converts the same z-slab it will later gather from
// (pairs-per-XCD = 1200 blocks; slab = 20 z-planes, matching st_half's map).
// ---------------------------------------------------------------------------
__global__ __launch_bounds__(256) void vol_to_half_kernel(
    const float4* __restrict__ vol, uint4* __restrict__ volh2)
{
    // 9600 blocks, 9600 % 8 == 0 -> bijective XCD chunking
    unsigned bid = blockIdx.x;
    unsigned nb  = (bid & 7u) * 1200u + (bid >> 3);
    int i = (int)(nb * 256u + threadIdx.x);   // pair index
    if (i >= NV / 2) return;
    f32x4 a = __builtin_nontemporal_load((const f32x4*)(vol + 2 * i));
    f32x4 b = __builtin_nontemporal_load((const f32x4*)(vol + 2 * i + 1));
    __half2 a01 = __floats2half2_rn(a.x, a.y);
    __half2 a23 = __floats2half2_rn(a.z, a.w);
    __half2 b01 = __floats2half2_rn(b.x, b.y);
    __half2 b23 = __floats2half2_rn(b.z, b.w);
    uint4 p;
    p.x = *(unsigned int*)&a01;
    p.y = *(unsigned int*)&a23;
    p.z = *(unsigned int*)&b01;
    p.w = *(unsigned int*)&b23;
    volh2[i] = p;
}

__device__ inline float4 h4_to_f4(uint2 p) {
    __half2 ab = *(__half2*)&p.x;
    __half2 cd = *(__half2*)&p.y;
    float2 f0 = __half22float2(ab);
    float2 f1 = __half22float2(cd);
    return make_float4(f0.x, f0.y, f1.x, f1.y);
}

// Load the (x0, x1) corner pair of one row with ONE 16-B load at the 8-B
// aligned address &row[a], a = min(ix0, W-2). For interior ix0 the halves are
// (v[ix0], v[ix0+1]); at the clamp edge (ix0 == W-1) we need (v[W-1], v[W-1]),
// i.e. (hi, hi). Note v_x1 is ALWAYS the high half.
__device__ inline void load_pair(const uint2* __restrict__ p, bool edge,
                                 float4& v0, float4& v1)
{
    u32x4 q;
    __builtin_memcpy(&q, p, 16);      // align-8 16B load (gfx950 unaligned-ok)
    uint2 lo, hi;
    lo.x = q[0]; lo.y = q[1];
    hi.x = q[2]; hi.y = q[3];
    float4 fl = h4_to_f4(lo);
    float4 fh = h4_to_f4(hi);
    v1 = fh;
    v0 = edge ? fh : fl;
}

// ---------------------------------------------------------------------------
// Pass 2: trilinear gather from half-packed volume.
// 1D grid (19200 blocks), XCD-chunked: XCD k owns z in [20k, 20k+20).
// Per-XCD gather working set ~5.2 MB ~ its 4 MiB L2; consecutive blocks
// within a slab share z0/z1 planes -> L2 hits instead of HBM refetch.
// ---------------------------------------------------------------------------
__global__ __launch_bounds__(256) void st_half_kernel(
    const uint2* __restrict__ volh,   // [D,H,W] of half4 (8 B)
    const float* __restrict__ df,     // [D,H,W,3]
    float*       __restrict__ out)    // [D,H,W,4] f32
{
    // 19200 blocks, 19200 % 8 == 0 -> bijective: nb = xcd*2400 + bid/8
    unsigned bid = blockIdx.x;
    unsigned nb  = (bid & 7u) * 2400u + (bid >> 3);
    int bx = (int)(nb % 10u);
    unsigned rest = nb / 10u;
    int by = (int)(rest % 48u);
    int bz = (int)(rest / 48u);

    int tid = threadIdx.x;
    int x = bx * 16 + (tid & 15);
    int y = by * 4  + ((tid >> 4) & 3);
    int z = bz * 4  + (tid >> 6);

    int idx = (z * H_ + y) * W_ + x;

    const float* dfp = df + 3 * (size_t)idx;
    float dz = __builtin_nontemporal_load(dfp + 0);
    float dy = __builtin_nontemporal_load(dfp + 1);
    float dx = __builtin_nontemporal_load(dfp + 2);

    float lz = (float)z + dz;
    float ly = (float)y + dy;
    float lx = (float)x + dx;

    // Reference semantics: loc0c = clip(floor(loc), 0, max); loc1 = clip(loc0c+1, 0, max)
    float z0f = fminf(fmaxf(floorf(lz), 0.f), (float)(D_ - 1));
    float y0f = fminf(fmaxf(floorf(ly), 0.f), (float)(H_ - 1));
    float x0f = fminf(fmaxf(floorf(lx), 0.f), (float)(W_ - 1));
    float z1f = fminf(z0f + 1.f, (float)(D_ - 1));
    float y1f = fminf(y0f + 1.f, (float)(H_ - 1));
    float x1f = fminf(x0f + 1.f, (float)(W_ - 1));

    float wz0 = z1f - lz, wz1 = 1.f - wz0;
    float wy0 = y1f - ly, wy1 = 1.f - wy0;
    float wx0 = x1f - lx, wx1 = 1.f - wx0;

    int iz0 = (int)z0f, iz1 = (int)z1f;
    int iy0 = (int)y0f, iy1 = (int)y1f;
    int ix0 = (int)x0f;

    bool edge = ix0 >= W_ - 1;
    int a = edge ? W_ - 2 : ix0;

    int b00 = (iz0 * H_ + iy0) * W_ + a;
    int b01 = (iz0 * H_ + iy1) * W_ + a;
    int b10 = (iz1 * H_ + iy0) * W_ + a;
    int b11 = (iz1 * H_ + iy1) * W_ + a;

    float4 v000, v001, v010, v011, v100, v101, v110, v111;
    load_pair(volh + b00, edge, v000, v001);
    load_pair(volh + b01, edge, v010, v011);
    load_pair(volh + b10, edge, v100, v101);
    load_pair(volh + b11, edge, v110, v111);

    float w000 = wz0 * wy0 * wx0;
    float w001 = wz0 * wy0 * wx1;
    float w010 = wz0 * wy1 * wx0;
    float w011 = wz0 * wy1 * wx1;
    float w100 = wz1 * wy0 * wx0;
    float w101 = wz1 * wy0 * wx1;
    float w110 = wz1 * wy1 * wx0;
    float w111 = wz1 * wy1 * wx1;

    f32x4 r;
    r.x = w000 * v000.x + w001 * v001.x + w010 * v010.x + w011 * v011.x
        + w100 * v100.x + w101 * v101.x + w110 * v110.x + w111 * v111.x;
    r.y = w000 * v000.y + w001 * v001.y + w010 * v010.y + w011 * v011.y
        + w100 * v100.y + w101 * v101.y + w110 * v110.y + w111 * v111.y;
    r.z = w000 * v000.z + w001 * v001.z + w010 * v010.z + w011 * v011.z
        + w100 * v100.z + w101 * v101.z + w110 * v110.z + w111 * v111.z;
    r.w = w000 * v000.w + w001 * v001.w + w010 * v010.w + w011 * v011.w
        + w100 * v100.w + w101 * v101.w + w110 * v110.w + w111 * v111.w;

    __builtin_nontemporal_store(r, (f32x4*)(out + 4 * (size_t)idx));
}

// ---------------------------------------------------------------------------
// Fallback (ws too small): round-2 pure-f32 gather kernel.
// ---------------------------------------------------------------------------
__global__ __launch_bounds__(256) void st_f32_kernel(
    const float4* __restrict__ vol,
    const float*  __restrict__ df,
    float4*       __restrict__ out)
{
    int tid = threadIdx.x;
    int x = blockIdx.x * 16 + (tid & 15);
    int y = blockIdx.y * 4  + ((tid >> 4) & 3);
    int z = blockIdx.z * 4  + (tid >> 6);
    int idx = (z * H_ + y) * W_ + x;

    float dz = df[3 * idx + 0];
    float dy = df[3 * idx + 1];
    float dx = df[3 * idx + 2];
    float lz = (float)z + dz, ly = (float)y + dy, lx = (float)x + dx;

    float z0f = fminf(fmaxf(floorf(lz), 0.f), (float)(D_ - 1));
    float y0f = fminf(fmaxf(floorf(ly), 0.f), (float)(H_ - 1));
    float x0f = fminf(fmaxf(floorf(lx), 0.f), (float)(W_ - 1));
    float z1f = fminf(z0f + 1.f, (float)(D_ - 1));
    float y1f = fminf(y0f + 1.f, (float)(H_ - 1));
    float x1f = fminf(x0f + 1.f, (float)(W_ - 1));

    float wz0 = z1f - lz, wz1 = 1.f - wz0;
    float wy0 = y1f - ly, wy1 = 1.f - wy0;
    float wx0 = x1f - lx, wx1 = 1.f - wx0;

    int iz0 = (int)z0f, iz1 = (int)z1f;
    int iy0 = (int)y0f, iy1 = (int)y1f;
    int ix0 = (int)x0f, ix1 = (int)x1f;

    int b00 = (iz0 * H_ + iy0) * W_;
    int b01 = (iz0 * H_ + iy1) * W_;
    int b10 = (iz1 * H_ + iy0) * W_;
    int b11 = (iz1 * H_ + iy1) * W_;

    float4 v000 = vol[b00 + ix0];
    float4 v001 = vol[b00 + ix1];
    float4 v010 = vol[b01 + ix0];
    float4 v011 = vol[b01 + ix1];
    float4 v100 = vol[b10 + ix0];
    float4 v101 = vol[b10 + ix1];
    float4 v110 = vol[b11 + ix0];
    float4 v111 = vol[b11 + ix1];

    float w000 = wz0*wy0*wx0, w001 = wz0*wy0*wx1;
    float w010 = wz0*wy1*wx0, w011 = wz0*wy1*wx1;
    float w100 = wz1*wy0*wx0, w101 = wz1*wy0*wx1;
    float w110 = wz1*wy1*wx0, w111 = wz1*wy1*wx1;

    float4 r;
    r.x = w000*v000.x + w001*v001.x + w010*v010.x + w011*v011.x
        + w100*v100.x + w101*v101.x + w110*v110.x + w111*v111.x;
    r.y = w000*v000.y + w001*v001.y + w010*v010.y + w011*v011.y
        + w100*v100.y + w101*v101.y + w110*v110.y + w111*v111.y;
    r.z = w000*v000.z + w001*v001.z + w010*v010.z + w011*v011.z
        + w100*v100.z + w101*v101.z + w110*v110.z + w111*v111.z;
    r.w = w000*v000.w + w001*v001.w + w010*v010.w + w011*v011.w
        + w100*v100.w + w101*v101.w + w110*v110.w + w111*v111.w;

    out[idx] = r;
}

extern "C" void kernel_launch(void* const* d_in, const int* in_sizes, int n_in,
                              void* d_out, int out_size, void* d_ws, size_t ws_size,
                              hipStream_t stream) {
    const float4* vol = (const float4*)d_in[0];  // (160,192,160,4) f32
    const float*  df  = (const float*)d_in[1];   // (160,192,160,3) f32
    float4* out = (float4*)d_out;

    size_t need = (size_t)NV * 8;  // half4 per voxel
    if (ws_size >= need) {
        int pairs = NV / 2;                       // 2,457,600 -> 9600 blocks
        vol_to_half_kernel<<<pairs / 256, 256, 0, stream>>>(
            vol, (uint4*)d_ws);
        st_half_kernel<<<19200, 256, 0, stream>>>(
            (const uint2*)d_ws, df, (float*)out);
    } else {
        dim3 grid(W_ / 16, H_ / 4, D_ / 4);       // 10 x 48 x 40
        st_f32_kernel<<<grid, 256, 0, stream>>>(vol, df, out);
    }
}

// Round 4
// 211.453 us; speedup vs baseline: 1.0063x; 1.0063x over previous
//
#include <hip/hip_runtime.h>
#include <hip/hip_fp16.h>

#define D_ 160
#define H_ 192
#define W_ 160
constexpr int NV = D_ * H_ * W_;   // 4,915,200 (even)

typedef float        f32x4 __attribute__((ext_vector_type(4)));
typedef unsigned int u32x4 __attribute__((ext_vector_type(4)));

// ---------------------------------------------------------------------------
// Pass 1: convert vol f32[NV][4] -> packed half4 (uint2) in d_ws.
// 2 voxels/thread: 32 B read (non-temporal; read-once), 16 B write, coalesced.
// XCD-swizzled so each XCD converts the same z-slab it will later gather from.
// ---------------------------------------------------------------------------
__global__ __launch_bounds__(256) void vol_to_half_kernel(
    const float4* __restrict__ vol, uint4* __restrict__ volh2)
{
    // 9600 blocks, 9600 % 8 == 0 -> bijective XCD chunking
    unsigned bid = blockIdx.x;
    unsigned nb  = (bid & 7u) * 1200u + (bid >> 3);
    int i = (int)(nb * 256u + threadIdx.x);   // pair index
    if (i >= NV / 2) return;
    f32x4 a = __builtin_nontemporal_load((const f32x4*)(vol + 2 * i));
    f32x4 b = __builtin_nontemporal_load((const f32x4*)(vol + 2 * i + 1));
    __half2 a01 = __floats2half2_rn(a.x, a.y);
    __half2 a23 = __floats2half2_rn(a.z, a.w);
    __half2 b01 = __floats2half2_rn(b.x, b.y);
    __half2 b23 = __floats2half2_rn(b.z, b.w);
    uint4 p;
    p.x = *(unsigned int*)&a01;
    p.y = *(unsigned int*)&a23;
    p.z = *(unsigned int*)&b01;
    p.w = *(unsigned int*)&b23;
    volh2[i] = p;
}

__device__ inline float4 h4_to_f4(uint2 p) {
    __half2 ab = *(__half2*)&p.x;
    __half2 cd = *(__half2*)&p.y;
    float2 f0 = __half22float2(ab);
    float2 f1 = __half22float2(cd);
    return make_float4(f0.x, f0.y, f1.x, f1.y);
}

// Per-voxel gather setup: 4 row-pair base offsets + 6 weights.
// Edge trick: at the x-clamp edge (ix0 == W-1, both corners v[W-1], weights
// sum to 1) the reference result is exactly v[W-1]; we load row[W-2..W-1]
// and force (wx0,wx1) = (0,1) so the high half carries the whole weight.
// Low-side (lx < 0) needs no special case: ix0=0, ix1=1, extrapolation
// weights match the reference exactly.
struct VoxSetup {
    int b00, b01, b10, b11;
    float wz0, wz1, wy0, wy1, wx0, wx1;
};

__device__ inline VoxSetup setup_voxel(int x, int y, int z,
                                       float dz, float dy, float dx)
{
    float lz = (float)z + dz;
    float ly = (float)y + dy;
    float lx = (float)x + dx;

    // Reference: loc0c = clip(floor(loc), 0, max); loc1 = clip(loc0c+1, 0, max)
    float z0f = fminf(fmaxf(floorf(lz), 0.f), (float)(D_ - 1));
    float y0f = fminf(fmaxf(floorf(ly), 0.f), (float)(H_ - 1));
    float x0f = fminf(fmaxf(floorf(lx), 0.f), (float)(W_ - 1));
    float z1f = fminf(z0f + 1.f, (float)(D_ - 1));
    float y1f = fminf(y0f + 1.f, (float)(H_ - 1));
    float x1f = fminf(x0f + 1.f, (float)(W_ - 1));

    VoxSetup s;
    s.wz0 = z1f - lz; s.wz1 = 1.f - s.wz0;
    s.wy0 = y1f - ly; s.wy1 = 1.f - s.wy0;

    int ix0 = (int)x0f;
    bool edge = ix0 >= W_ - 1;
    int a = edge ? W_ - 2 : ix0;
    float wx0 = x1f - lx;
    s.wx0 = edge ? 0.f : wx0;   // edge: result is exactly the high half
    s.wx1 = 1.f - s.wx0;

    int iz0 = (int)z0f, iz1 = (int)z1f;
    int iy0 = (int)y0f, iy1 = (int)y1f;
    s.b00 = (iz0 * H_ + iy0) * W_ + a;
    s.b01 = (iz0 * H_ + iy1) * W_ + a;
    s.b10 = (iz1 * H_ + iy0) * W_ + a;
    s.b11 = (iz1 * H_ + iy1) * W_ + a;
    return s;
}

// Reduce 4 loaded row-pairs (lo = x0 corner, hi = x1 corner) with weights.
__device__ inline f32x4 reduce_voxel(const VoxSetup& s,
                                     u32x4 q00, u32x4 q01, u32x4 q10, u32x4 q11)
{
    uint2 l00, h00, l01, h01, l10, h10, l11, h11;
    l00.x = q00[0]; l00.y = q00[1]; h00.x = q00[2]; h00.y = q00[3];
    l01.x = q01[0]; l01.y = q01[1]; h01.x = q01[2]; h01.y = q01[3];
    l10.x = q10[0]; l10.y = q10[1]; h10.x = q10[2]; h10.y = q10[3];
    l11.x = q11[0]; l11.y = q11[1]; h11.x = q11[2]; h11.y = q11[3];

    float4 v000 = h4_to_f4(l00), v001 = h4_to_f4(h00);
    float4 v010 = h4_to_f4(l01), v011 = h4_to_f4(h01);
    float4 v100 = h4_to_f4(l10), v101 = h4_to_f4(h10);
    float4 v110 = h4_to_f4(l11), v111 = h4_to_f4(h11);

    float w000 = s.wz0 * s.wy0 * s.wx0;
    float w001 = s.wz0 * s.wy0 * s.wx1;
    float w010 = s.wz0 * s.wy1 * s.wx0;
    float w011 = s.wz0 * s.wy1 * s.wx1;
    float w100 = s.wz1 * s.wy0 * s.wx0;
    float w101 = s.wz1 * s.wy0 * s.wx1;
    float w110 = s.wz1 * s.wy1 * s.wx0;
    float w111 = s.wz1 * s.wy1 * s.wx1;

    f32x4 r;
    r.x = w000 * v000.x + w001 * v001.x + w010 * v010.x + w011 * v011.x
        + w100 * v100.x + w101 * v101.x + w110 * v110.x + w111 * v111.x;
    r.y = w000 * v000.y + w001 * v001.y + w010 * v010.y + w011 * v011.y
        + w100 * v100.y + w101 * v101.y + w110 * v110.y + w111 * v111.y;
    r.z = w000 * v000.z + w001 * v001.z + w010 * v010.z + w011 * v011.z
        + w100 * v100.z + w101 * v101.z + w110 * v110.z + w111 * v111.z;
    r.w = w000 * v000.w + w001 * v001.w + w010 * v010.w + w011 * v011.w
        + w100 * v100.w + w101 * v101.w + w110 * v110.w + w111 * v111.w;
    return r;
}

// ---------------------------------------------------------------------------
// Pass 2: trilinear gather, 2 voxels/thread (x and x+16) for 2x memory-level
// parallelism: 8 paired 16-B gathers + 2 df loads in flight per thread before
// any interpolation. Block footprint 32x4x4 -> grid 5*48*40 = 9600 blocks,
// XCD-chunked (1200/XCD): XCD k owns z in [20k, 20k+20) -> per-XCD gather
// working set ~5 MB ~ its L2.
// ---------------------------------------------------------------------------
__global__ __launch_bounds__(256) void st_half_kernel(
    const uint2* __restrict__ volh,   // [D,H,W] of half4 (8 B)
    const float* __restrict__ df,     // [D,H,W,3]
    float*       __restrict__ out)    // [D,H,W,4] f32
{
    // 9600 blocks, 9600 % 8 == 0 -> bijective: nb = xcd*1200 + bid/8
    unsigned bid = blockIdx.x;
    unsigned nb  = (bid & 7u) * 1200u + (bid >> 3);
    int bx = (int)(nb % 5u);           // 5 x-tiles of 32
    unsigned rest = nb / 5u;           // 0..1919
    int by = (int)(rest % 48u);
    int bz = (int)(rest / 48u);        // 0..39

    int tid = threadIdx.x;
    int xA = bx * 32 + (tid & 15);
    int y  = by * 4  + ((tid >> 4) & 3);
    int z  = bz * 4  + (tid >> 6);

    int idxA = (z * H_ + y) * W_ + xA;
    int idxB = idxA + 16;

    const float* dfpA = df + 3 * (size_t)idxA;
    const float* dfpB = df + 3 * (size_t)idxB;
    float dzA = __builtin_nontemporal_load(dfpA + 0);
    float dyA = __builtin_nontemporal_load(dfpA + 1);
    float dxA = __builtin_nontemporal_load(dfpA + 2);
    float dzB = __builtin_nontemporal_load(dfpB + 0);
    float dyB = __builtin_nontemporal_load(dfpB + 1);
    float dxB = __builtin_nontemporal_load(dfpB + 2);

    VoxSetup sA = setup_voxel(xA,      y, z, dzA, dyA, dxA);
    VoxSetup sB = setup_voxel(xA + 16, y, z, dzB, dyB, dxB);

    // Issue all 8 gathers before any reduction (ILP / MLP).
    u32x4 qA00, qA01, qA10, qA11, qB00, qB01, qB10, qB11;
    __builtin_memcpy(&qA00, volh + sA.b00, 16);
    __builtin_memcpy(&qA01, volh + sA.b01, 16);
    __builtin_memcpy(&qA10, volh + sA.b10, 16);
    __builtin_memcpy(&qA11, volh + sA.b11, 16);
    __builtin_memcpy(&qB00, volh + sB.b00, 16);
    __builtin_memcpy(&qB01, volh + sB.b01, 16);
    __builtin_memcpy(&qB10, volh + sB.b10, 16);
    __builtin_memcpy(&qB11, volh + sB.b11, 16);

    f32x4 rA = reduce_voxel(sA, qA00, qA01, qA10, qA11);
    __builtin_nontemporal_store(rA, (f32x4*)(out + 4 * (size_t)idxA));
    f32x4 rB = reduce_voxel(sB, qB00, qB01, qB10, qB11);
    __builtin_nontemporal_store(rB, (f32x4*)(out + 4 * (size_t)idxB));
}

// ---------------------------------------------------------------------------
// Fallback (ws too small): pure-f32 gather kernel.
// ---------------------------------------------------------------------------
__global__ __launch_bounds__(256) void st_f32_kernel(
    const float4* __restrict__ vol,
    const float*  __restrict__ df,
    float4*       __restrict__ out)
{
    int tid = threadIdx.x;
    int x = blockIdx.x * 16 + (tid & 15);
    int y = blockIdx.y * 4  + ((tid >> 4) & 3);
    int z = blockIdx.z * 4  + (tid >> 6);
    int idx = (z * H_ + y) * W_ + x;

    float dz = df[3 * idx + 0];
    float dy = df[3 * idx + 1];
    float dx = df[3 * idx + 2];
    float lz = (float)z + dz, ly = (float)y + dy, lx = (float)x + dx;

    float z0f = fminf(fmaxf(floorf(lz), 0.f), (float)(D_ - 1));
    float y0f = fminf(fmaxf(floorf(ly), 0.f), (float)(H_ - 1));
    float x0f = fminf(fmaxf(floorf(lx), 0.f), (float)(W_ - 1));
    float z1f = fminf(z0f + 1.f, (float)(D_ - 1));
    float y1f = fminf(y0f + 1.f, (float)(H_ - 1));
    float x1f = fminf(x0f + 1.f, (float)(W_ - 1));

    float wz0 = z1f - lz, wz1 = 1.f - wz0;
    float wy0 = y1f - ly, wy1 = 1.f - wy0;
    float wx0 = x1f - lx, wx1 = 1.f - wx0;

    int iz0 = (int)z0f, iz1 = (int)z1f;
    int iy0 = (int)y0f, iy1 = (int)y1f;
    int ix0 = (int)x0f, ix1 = (int)x1f;

    int b00 = (iz0 * H_ + iy0) * W_;
    int b01 = (iz0 * H_ + iy1) * W_;
    int b10 = (iz1 * H_ + iy0) * W_;
    int b11 = (iz1 * H_ + iy1) * W_;

    float4 v000 = vol[b00 + ix0];
    float4 v001 = vol[b00 + ix1];
    float4 v010 = vol[b01 + ix0];
    float4 v011 = vol[b01 + ix1];
    float4 v100 = vol[b10 + ix0];
    float4 v101 = vol[b10 + ix1];
    float4 v110 = vol[b11 + ix0];
    float4 v111 = vol[b11 + ix1];

    float w000 = wz0*wy0*wx0, w001 = wz0*wy0*wx1;
    float w010 = wz0*wy1*wx0, w011 = wz0*wy1*wx1;
    float w100 = wz1*wy0*wx0, w101 = wz1*wy0*wx1;
    float w110 = wz1*wy1*wx0, w111 = wz1*wy1*wx1;

    float4 r;
    r.x = w000*v000.x + w001*v001.x + w010*v010.x + w011*v011.x
        + w100*v100.x + w101*v101.x + w110*v110.x + w111*v111.x;
    r.y = w000*v000.y + w001*v001.y + w010*v010.y + w011*v011.y
        + w100*v100.y + w101*v101.y + w110*v110.y + w111*v111.y;
    r.z = w000*v000.z + w001*v001.z + w010*v010.z + w011*v011.z
        + w100*v100.z + w101*v101.z + w110*v110.z + w111*v111.z;
    r.w = w000*v000.w + w001*v001.w + w010*v010.w + w011*v011.w
        + w100*v100.w + w101*v101.w + w110*v110.w + w111*v111.w;

    out[idx] = r;
}

extern "C" void kernel_launch(void* const* d_in, const int* in_sizes, int n_in,
                              void* d_out, int out_size, void* d_ws, size_t ws_size,
                              hipStream_t stream) {
    const float4* vol = (const float4*)d_in[0];  // (160,192,160,4) f32
    const float*  df  = (const float*)d_in[1];   // (160,192,160,3) f32
    float4* out = (float4*)d_out;

    size_t need = (size_t)NV * 8;  // half4 per voxel
    if (ws_size >= need) {
        int pairs = NV / 2;                       // 2,457,600 -> 9600 blocks
        vol_to_half_kernel<<<pairs / 256, 256, 0, stream>>>(
            vol, (uint4*)d_ws);
        st_half_kernel<<<9600, 256, 0, stream>>>(
            (const uint2*)d_ws, df, (float*)out);
    } else {
        dim3 grid(W_ / 16, H_ / 4, D_ / 4);       // 10 x 48 x 40
        st_f32_kernel<<<grid, 256, 0, stream>>>(vol, df, out);
    }
}